// Round 3
// baseline (428.828 us; speedup 1.0000x reference)
//
#include <hip/hip_runtime.h>

// Sorted-segment product: out[i] = prod_{j: csr[j]==i} x[ptrs[j]], empty -> 0.
//
// R7: no windows. Three rounds established:
//   R4 (189us): windowed + per-window LDS consume -> vmcnt(0) convoy per
//     window, latency-bound at 29% HBM.
//   R5 (233us): sorted quartiles -> noisy order statistics, FETCH 778MB,
//     BW-bound on wasted traffic.
//   R6 (227us): windowed, deferred consume -> masked loads re-writing g[k]
//     across a runtime loop = WAW hazard -> compiler spills g[] to scratch
//     (WRITE 43->157MB, VGPR=32). Predication + deferred consume is
//     compiler-hostile.
// x is 16.8MB -> fully L3-resident (256MiB). The windowing only ever saved
// L2<->L3 traffic, never HBM. So: UNCONDITIONAL 16-deep-MLP gather (each
// g[k] written exactly once, no predication, no barriers), one staged drain
// at the LDS mirror, then the proven run-ownership product phase.
// ~50 VGPR, 4 blocks/CU (32KB LDS), 100% occupancy, plain 2048-block grid.

#define EPT       16              // edges per thread
#define EPT_SHIFT 4
#define BLK       512             // threads per block (8 waves)
#define MSC       (BLK * EPT)     // 8192 edges per block

__global__ __launch_bounds__(BLK, 8) void prodseg_main(
    const float* __restrict__ x,
    const int*   __restrict__ ptrs,
    const int*   __restrict__ csr,
    float*       __restrict__ out,
    int E, int S)
{
    __shared__ float gbuf[MSC];   // column-major: edge (t,k) -> gbuf[k*BLK + t]
    const int t = threadIdx.x;
    const int sbase = (int)blockIdx.x * MSC;
    const int gbase = sbase + t * EPT;

    // ---- stage my 16 ptrs into registers (vectorized, aligned) ----
    int pt[EPT];
    {
        const int4* p4 = reinterpret_cast<const int4*>(ptrs + gbase);
        #pragma unroll
        for (int i = 0; i < EPT / 4; ++i) {
            int4 v = p4[i];
            pt[4*i+0] = v.x; pt[4*i+1] = v.y;
            pt[4*i+2] = v.z; pt[4*i+3] = v.w;
        }
    }

    // ---- unconditional gather: 16 independent loads, full MLP ----
    // No predication, no barriers; x is L3-resident so misses are cheap.
    // Each g[k] is written exactly once -> clean SSA, no spill pressure.
    float g[EPT];
    #pragma unroll
    for (int k = 0; k < EPT; ++k)
        g[k] = x[pt[k]];

    // ---- single staged drain: mirror to LDS for cross-thread run walks ----
    // Compiler emits descending vmcnt waits here (vmcnt(15)..vmcnt(0));
    // by the time the first write waits, most loads have landed.
    #pragma unroll
    for (int k = 0; k < EPT; ++k)
        gbuf[k * BLK + t] = g[k];
    __syncthreads();

    // ---- product phase (run ownership, exact; R1/R4-proven) ----
    int prev = (gbase == 0) ? -1 : csr[gbase - 1];
    const int4* c4 = reinterpret_cast<const int4*>(csr + gbase);
    int cur = 0; bool own = false; float prod = 1.0f;
    #pragma unroll
    for (int i = 0; i < EPT / 4; ++i) {
        int4 c = c4[i];
        int sv[4] = {c.x, c.y, c.z, c.w};
        #pragma unroll
        for (int j = 0; j < 4; ++j) {
            const int k = 4 * i + j;
            int sg = sv[j];
            if (k == 0) {
                cur = sg; own = (sg != prev);
                prod = own ? g[0] : 1.0f;
                if (own)
                    for (int q = prev + 1; q < cur; ++q) out[q] = 0.0f;
            } else {
                if (sg == cur) {
                    prod *= g[k];          // harmless if !own (never stored)
                } else {
                    if (own) out[cur] = prod;
                    for (int q = cur + 1; q < sg; ++q) out[q] = 0.0f;
                    cur = sg; own = true; prod = g[k];
                }
            }
        }
    }
    // final run: walk forward; in-block values come from LDS
    if (own) {
        int idx = gbase + EPT;
        while (idx < E) {
            if (csr[idx] != cur) break;
            float v;
            int local = idx - sbase;
            if (local < MSC)
                v = gbuf[(local & (EPT - 1)) * BLK + (local >> EPT_SHIFT)];
            else
                v = x[ptrs[idx]];
            prod *= v; ++idx;
        }
        out[cur] = prod;
        if (idx == E)
            for (int q = cur + 1; q < S; ++q) out[q] = 0.0f;
    }
}

// Generic tail (E % MSC != 0) — R1-proven logic; not launched for E = 2^24.
#define TK 8
__global__ __launch_bounds__(256) void prodseg_tail(
    const float* __restrict__ x,
    const int*   __restrict__ ptrs,
    const int*   __restrict__ csr,
    float*       __restrict__ out,
    int E0, int E, int S)
{
    int t = blockIdx.x * blockDim.x + threadIdx.x;
    int base = E0 + t * TK;
    if (base >= E) return;
    int prev = (base == 0) ? -1 : csr[base - 1];
    int n = (base + TK <= E) ? TK : (E - base);

    int cur = 0; bool own = false; float prod = 1.0f;
    for (int k = 0; k < n; ++k) {
        int sg = csr[base + k];
        float gv = x[ptrs[base + k]];
        if (k == 0) {
            cur = sg; own = (sg != prev);
            prod = own ? gv : 1.0f;
            if (own) for (int q = prev + 1; q < cur; ++q) out[q] = 0.0f;
        } else if (sg == cur) {
            prod *= gv;
        } else {
            if (own) out[cur] = prod;
            for (int q = cur + 1; q < sg; ++q) out[q] = 0.0f;
            cur = sg; own = true; prod = gv;
        }
    }
    if (own) {
        int idx = base + n;
        while (idx < E && csr[idx] == cur) { prod *= x[ptrs[idx]]; ++idx; }
        out[cur] = prod;
        if (idx == E) for (int q = cur + 1; q < S; ++q) out[q] = 0.0f;
    }
}

extern "C" void kernel_launch(void* const* d_in, const int* in_sizes, int n_in,
                              void* d_out, int out_size, void* d_ws, size_t ws_size,
                              hipStream_t stream) {
    const float* x    = (const float*)d_in[0];
    const int*   ptrs = (const int*)d_in[1];
    const int*   csr  = (const int*)d_in[2];
    float*       out  = (float*)d_out;
    int E = in_sizes[1];
    int S = out_size;

    int F  = E / MSC;                                   // full blocks
    int E0 = F * MSC;

    if (F > 0)
        prodseg_main<<<F, BLK, 0, stream>>>(x, ptrs, csr, out, E, S);
    if (E0 < E) {
        int nt = (E - E0 + TK - 1) / TK;
        prodseg_tail<<<(nt + 255) / 256, 256, 0, stream>>>(x, ptrs, csr, out, E0, E, S);
    }
}

// Round 4
// 306.734 us; speedup vs baseline: 1.3980x; 1.3980x over previous
//
#include <hip/hip_runtime.h>

// Sorted-segment product: out[i] = prod_{j: csr[j]==i} x[ptrs[j]], empty -> 0.
//
// R8: block-level exact binning (counting sort by 1MB window) + phase-
// pipelined unconditional gather + run-summary combine (no value mirror).
//
// Established facts (R4-R7):
//   - fabric/L3 wall ~3.5 TB/s for gather traffic; time = traffic / 3.5.
//   - unwindowed gather: 1.045 GB -> 332us (R7). Windowed: ~400 MB possible.
//   - predicated window code can't avoid drains (R4) or spills (R6).
// Fix: counting-sort the block's ptrs into window bins in LDS. The binned
// list is window-sorted, so fixed 512-entry phases are window-monotone,
// UNCONDITIONAL (1 load/thread/phase), and software-pipelined (ds_write of
// phase j waits on the load issued in phase j-1 -> already landed; ptr
// ds_read prefetched one phase ahead). Raw s_barrier paces waves for L2
// locality; slot ownership is exclusive so no barrier is needed for
// correctness. Values overwrite the ptr list in place; threads unbin their
// own 16 via positions kept in registers (packed u16).
// Cross-thread runs: per-thread summaries {first_seg|span<<31, first_prod}
// (4KB) replace the 32KB gbuf mirror; tail walk steps threads, not edges.
// LDS 37KB -> 4 blocks/CU (BLK=512), 32 waves/CU, 8.4M edges resident
// grid-wide -> 2 x-passes -> ~400MB total traffic.

#define EPT       16              // edges per thread
#define BLK       512             // threads per block (8 waves)
#define MSC       (BLK * EPT)     // 8192 edges per block
#define NWIN      16              // bins (1MB windows for N=2^22)
#define NPH       (MSC / BLK)     // 16 gather phases, 1 entry/thread each

__global__ __launch_bounds__(BLK, 8) void prodseg_main(
    const float* __restrict__ x,
    const int*   __restrict__ ptrs,
    const int*   __restrict__ csr,
    float*       __restrict__ out,
    int E, int S, int wshift)
{
    __shared__ int      list[MSC];     // ptr, overwritten with value bits
    __shared__ unsigned hist[NWIN];
    __shared__ unsigned cursor[NWIN];
    __shared__ unsigned fs[BLK];       // first seg | (span ? 1<<31 : 0)
    __shared__ float    fp[BLK];       // first-run product

    const int t = threadIdx.x;
    const int sbase = (int)blockIdx.x * MSC;
    const int gbase = sbase + t * EPT;

    if (t < NWIN) hist[t] = 0u;
    __syncthreads();

    // ---- stage my 16 ptrs (vectorized, 64B-aligned) ----
    int pt[EPT];
    {
        const int4* p4 = reinterpret_cast<const int4*>(ptrs + gbase);
        #pragma unroll
        for (int i = 0; i < EPT / 4; ++i) {
            int4 v = p4[i];
            pt[4*i+0] = v.x; pt[4*i+1] = v.y;
            pt[4*i+2] = v.z; pt[4*i+3] = v.w;
        }
    }

    // ---- histogram by window ----
    #pragma unroll
    for (int k = 0; k < EPT; ++k) {
        unsigned w = (unsigned)pt[k] >> wshift;
        w = w < NWIN ? w : NWIN - 1;
        atomicAdd(&hist[w], 1u);
    }
    __syncthreads();

    // ---- exclusive scan (16 values, thread 0) -> cursors ----
    if (t == 0) {
        unsigned acc = 0;
        #pragma unroll
        for (int w = 0; w < NWIN; ++w) { unsigned c = hist[w]; cursor[w] = acc; acc += c; }
    }
    __syncthreads();

    // ---- scatter ptrs into window-sorted list; keep my positions ----
    unsigned mp[EPT / 2];              // packed u16 pairs
    #pragma unroll
    for (int k = 0; k < EPT; ++k) {
        unsigned w = (unsigned)pt[k] >> wshift;
        w = w < NWIN ? w : NWIN - 1;
        unsigned pos = atomicAdd(&cursor[w], 1u);
        list[pos] = pt[k];
        if ((k & 1) == 0) mp[k >> 1] = pos;
        else              mp[k >> 1] |= pos << 16;
    }
    __syncthreads();

    // ---- phased gather over the window-sorted list ----
    // Phase j: entry j*BLK + t. Unconditional, window-monotone. Pipeline:
    // issue phase-j load (ptr prefetched), prefetch phase-(j+1) ptr, then
    // write phase-(j-1)'s value (its load landed a full phase ago).
    // Slot (m*BLK+t) is read (iter m+1's prefetch path) and written
    // (iter m+1) only by thread t -> race-free without barriers; the raw
    // s_barrier only paces waves so the block marches windows together.
    {
        int   p0 = list[t];            // phase 0 ptr
        float v0 = x[p0];              // phase 0 load in flight
        int   p1 = list[BLK + t];      // phase 1 ptr prefetched
        #pragma unroll
        for (int j = 1; j < NPH; ++j) {
            float vj = x[p1];                                  // issue phase j
            int pn = (j + 1 < NPH) ? list[(j + 1) * BLK + t] : 0;
            list[(j - 1) * BLK + t] = __float_as_int(v0);      // consume j-1
            v0 = vj; p1 = pn;
            __builtin_amdgcn_s_barrier();                      // pace, no drain
        }
        list[(NPH - 1) * BLK + t] = __float_as_int(v0);
    }
    __syncthreads();                   // values visible to unbin (cross-thread)

    // ---- unbin my 16 values ----
    float g[EPT];
    #pragma unroll
    for (int k = 0; k < EPT; ++k) {
        unsigned pos = (k & 1) ? (mp[k >> 1] >> 16) : (mp[k >> 1] & 0xffffu);
        g[k] = __int_as_float(list[pos]);
    }

    // ---- product phase: local runs + first-run summary ----
    int prev = (gbase == 0) ? -1 : csr[gbase - 1];
    const int4* c4 = reinterpret_cast<const int4*>(csr + gbase);
    int cur = 0; bool own = false, rec = false; float prod = 1.0f;
    #pragma unroll
    for (int i = 0; i < EPT / 4; ++i) {
        int4 c = c4[i];
        int sv[4] = {c.x, c.y, c.z, c.w};
        #pragma unroll
        for (int j = 0; j < 4; ++j) {
            const int k = 4 * i + j;
            int sg = sv[j];
            if (k == 0) {
                cur = sg; own = (sg != prev);
                prod = g[0];           // FULL head product (even if !own)
                if (own)
                    for (int q = prev + 1; q < cur; ++q) out[q] = 0.0f;
            } else if (sg == cur) {
                prod *= g[k];
            } else {
                if (!rec) { fs[t] = (unsigned)cur; fp[t] = prod; rec = true; }
                if (own) out[cur] = prod;
                for (int q = cur + 1; q < sg; ++q) out[q] = 0.0f;
                cur = sg; own = true; prod = g[k];
            }
        }
    }
    if (!rec) { fs[t] = (unsigned)cur | 0x80000000u; fp[t] = prod; }
    __syncthreads();

    // ---- tail walk over THREAD summaries (avg <1 step) ----
    if (own) {
        bool past = true;              // run continues past the block?
        for (int u = t + 1; u < BLK; ++u) {
            unsigned f = fs[u];
            if ((int)(f & 0x7fffffffu) != cur) { past = false; break; }
            prod *= fp[u];
            if (!(f & 0x80000000u)) { past = false; break; }
        }
        if (past) {
            // rare: run crosses the block boundary -> finish in global
            int idx = sbase + MSC;
            while (idx < E && csr[idx] == cur) { prod *= x[ptrs[idx]]; ++idx; }
            out[cur] = prod;
            if (idx == E)
                for (int q = cur + 1; q < S; ++q) out[q] = 0.0f;
        } else {
            out[cur] = prod;
        }
    }
}

// Generic tail (E % MSC != 0) — R1-proven logic; not launched for E = 2^24.
#define TK 8
__global__ __launch_bounds__(256) void prodseg_tail(
    const float* __restrict__ x,
    const int*   __restrict__ ptrs,
    const int*   __restrict__ csr,
    float*       __restrict__ out,
    int E0, int E, int S)
{
    int t = blockIdx.x * blockDim.x + threadIdx.x;
    int base = E0 + t * TK;
    if (base >= E) return;
    int prev = (base == 0) ? -1 : csr[base - 1];
    int n = (base + TK <= E) ? TK : (E - base);

    int cur = 0; bool own = false; float prod = 1.0f;
    for (int k = 0; k < n; ++k) {
        int sg = csr[base + k];
        float gv = x[ptrs[base + k]];
        if (k == 0) {
            cur = sg; own = (sg != prev);
            prod = own ? gv : 1.0f;
            if (own) for (int q = prev + 1; q < cur; ++q) out[q] = 0.0f;
        } else if (sg == cur) {
            prod *= gv;
        } else {
            if (own) out[cur] = prod;
            for (int q = cur + 1; q < sg; ++q) out[q] = 0.0f;
            cur = sg; own = true; prod = gv;
        }
    }
    if (own) {
        int idx = base + n;
        while (idx < E && csr[idx] == cur) { prod *= x[ptrs[idx]]; ++idx; }
        out[cur] = prod;
        if (idx == E) for (int q = cur + 1; q < S; ++q) out[q] = 0.0f;
    }
}

extern "C" void kernel_launch(void* const* d_in, const int* in_sizes, int n_in,
                              void* d_out, int out_size, void* d_ws, size_t ws_size,
                              hipStream_t stream) {
    const float* x    = (const float*)d_in[0];
    const int*   ptrs = (const int*)d_in[1];
    const int*   csr  = (const int*)d_in[2];
    float*       out  = (float*)d_out;
    int N = in_sizes[0];
    int E = in_sizes[1];
    int S = out_size;

    // smallest shift with (N-1)>>shift < NWIN  (18 for N = 2^22 -> 1MB windows)
    int wshift = 0;
    while (((unsigned)(N - 1) >> wshift) >= NWIN) ++wshift;

    int F  = E / MSC;                  // full blocks
    int E0 = F * MSC;

    if (F > 0)
        prodseg_main<<<F, BLK, 0, stream>>>(x, ptrs, csr, out, E, S, wshift);
    if (E0 < E) {
        int nt = (E - E0 + TK - 1) / TK;
        prodseg_tail<<<(nt + 255) / 256, 256, 0, stream>>>(x, ptrs, csr, out, E0, E, S);
    }
}

// Round 5
// 304.916 us; speedup vs baseline: 1.4064x; 1.0060x over previous
//
#include <hip/hip_runtime.h>

// Sorted-segment product: out[i] = prod_{j: csr[j]==i} x[ptrs[j]], empty -> 0.
//
// R9 = R8's binned pipelined gather + exactly-resident launch schedule.
//
// Established (R4-R8):
//   - fabric/L3 wall ~3.5-3.7 TB/s for gather traffic; time = traffic/wall.
//   - R8 (198us): block-level counting-sort by window + unconditional
//     1-load/thread phases + run-summary combine works: zero drains, wall
//     speed. But FETCH 652MB = 3.8 x-passes: 2048 transient blocks over
//     1024 residency slots -> continuous back-fill churn -> ~6 live
//     windows/XCD (6MB > 4MiB L2) -> thrash.
//   - R4's persistent grid (all blocks co-resident, marching together)
//     reached ~1.5 x-passes with the same windows.
// Fix:
//   (a) grid == residency capacity (1024 = 4/CU x 256CU; 37KB LDS -> 4/CU),
//       F/1024 = 2 sequential launches; the launch boundary is a free grid
//       barrier separating the two x-passes.
//   (b) NWIN 16 -> 32 (512KB windows): live set = drift x 0.5MB << 4MiB L2.
//   (c) gather pipeline depth 1 -> 2 (consume j-2 while issuing j).

#define EPT       16              // edges per thread
#define BLK       512             // threads per block (8 waves)
#define MSC       (BLK * EPT)     // 8192 edges per block
#define NWIN      32              // bins (512KB windows for N=2^22)
#define NPH       (MSC / BLK)     // 16 gather phases, 1 entry/thread each
#define NBLK      1024            // co-residency capacity: 4 blocks/CU

__global__ __launch_bounds__(BLK, 8) void prodseg_main(
    const float* __restrict__ x,
    const int*   __restrict__ ptrs,
    const int*   __restrict__ csr,
    float*       __restrict__ out,
    int E, int S, int wshift, int scbase, int F)
{
    __shared__ int      list[MSC];     // ptr, overwritten with value bits
    __shared__ unsigned hist[NWIN];
    __shared__ unsigned cursor[NWIN];
    __shared__ unsigned fs[BLK];       // first seg | (span ? 1<<31 : 0)
    __shared__ float    fp[BLK];       // first-run product

    const int sc = scbase + (int)blockIdx.x;
    if (sc >= F) return;               // block-uniform
    const int t = threadIdx.x;
    const int sbase = sc * MSC;
    const int gbase = sbase + t * EPT;

    if (t < NWIN) hist[t] = 0u;
    __syncthreads();

    // ---- stage my 16 ptrs (vectorized, 64B-aligned) ----
    int pt[EPT];
    {
        const int4* p4 = reinterpret_cast<const int4*>(ptrs + gbase);
        #pragma unroll
        for (int i = 0; i < EPT / 4; ++i) {
            int4 v = p4[i];
            pt[4*i+0] = v.x; pt[4*i+1] = v.y;
            pt[4*i+2] = v.z; pt[4*i+3] = v.w;
        }
    }

    // ---- histogram by window ----
    #pragma unroll
    for (int k = 0; k < EPT; ++k) {
        unsigned w = (unsigned)pt[k] >> wshift;
        w = w < NWIN ? w : NWIN - 1;
        atomicAdd(&hist[w], 1u);
    }
    __syncthreads();

    // ---- exclusive scan (NWIN values, thread 0) -> cursors ----
    if (t == 0) {
        unsigned acc = 0;
        #pragma unroll
        for (int w = 0; w < NWIN; ++w) { unsigned c = hist[w]; cursor[w] = acc; acc += c; }
    }
    __syncthreads();

    // ---- scatter ptrs into window-sorted list; keep my positions ----
    unsigned mp[EPT / 2];              // packed u16 pairs
    #pragma unroll
    for (int k = 0; k < EPT; ++k) {
        unsigned w = (unsigned)pt[k] >> wshift;
        w = w < NWIN ? w : NWIN - 1;
        unsigned pos = atomicAdd(&cursor[w], 1u);
        list[pos] = pt[k];
        if ((k & 1) == 0) mp[k >> 1] = pos;
        else              mp[k >> 1] |= pos << 16;
    }
    __syncthreads();

    // ---- phased gather over the window-sorted list (depth-2 pipeline) ----
    // Phase j: entry j*BLK + t. Unconditional, window-monotone. Consume
    // phase j-2's value while issuing phase j -> each load has two full
    // phases to land. Slot (m*BLK+t) is touched only by thread t between
    // barriers -> race-free; raw s_barrier paces waves (L2 locality), no
    // vmcnt drain.
    {
        int   pa = list[t];
        int   pb = list[BLK + t];
        float va = x[pa];              // phase 0 in flight
        float vb = x[pb];              // phase 1 in flight
        int   pc = list[2 * BLK + t];  // phase 2 ptr
        #pragma unroll
        for (int j = 2; j < NPH; ++j) {
            float vc = x[pc];                                  // issue phase j
            int pn = (j + 1 < NPH) ? list[(j + 1) * BLK + t] : 0;
            list[(j - 2) * BLK + t] = __float_as_int(va);      // consume j-2
            va = vb; vb = vc; pc = pn;
            __builtin_amdgcn_s_barrier();                      // pace, no drain
        }
        list[(NPH - 2) * BLK + t] = __float_as_int(va);
        list[(NPH - 1) * BLK + t] = __float_as_int(vb);
    }
    __syncthreads();                   // values visible to unbin (cross-thread)

    // ---- unbin my 16 values ----
    float g[EPT];
    #pragma unroll
    for (int k = 0; k < EPT; ++k) {
        unsigned pos = (k & 1) ? (mp[k >> 1] >> 16) : (mp[k >> 1] & 0xffffu);
        g[k] = __int_as_float(list[pos]);
    }

    // ---- product phase: local runs + first-run summary ----
    int prev = (gbase == 0) ? -1 : csr[gbase - 1];
    const int4* c4 = reinterpret_cast<const int4*>(csr + gbase);
    int cur = 0; bool own = false, rec = false; float prod = 1.0f;
    #pragma unroll
    for (int i = 0; i < EPT / 4; ++i) {
        int4 c = c4[i];
        int sv[4] = {c.x, c.y, c.z, c.w};
        #pragma unroll
        for (int j = 0; j < 4; ++j) {
            const int k = 4 * i + j;
            int sg = sv[j];
            if (k == 0) {
                cur = sg; own = (sg != prev);
                prod = g[0];           // FULL head product (even if !own)
                if (own)
                    for (int q = prev + 1; q < cur; ++q) out[q] = 0.0f;
            } else if (sg == cur) {
                prod *= g[k];
            } else {
                if (!rec) { fs[t] = (unsigned)cur; fp[t] = prod; rec = true; }
                if (own) out[cur] = prod;
                for (int q = cur + 1; q < sg; ++q) out[q] = 0.0f;
                cur = sg; own = true; prod = g[k];
            }
        }
    }
    if (!rec) { fs[t] = (unsigned)cur | 0x80000000u; fp[t] = prod; }
    __syncthreads();

    // ---- tail walk over THREAD summaries (avg <1 step) ----
    if (own) {
        bool past = true;              // run continues past the block?
        for (int u = t + 1; u < BLK; ++u) {
            unsigned f = fs[u];
            if ((int)(f & 0x7fffffffu) != cur) { past = false; break; }
            prod *= fp[u];
            if (!(f & 0x80000000u)) { past = false; break; }
        }
        if (past) {
            // rare: run crosses the block boundary -> finish in global
            int idx = sbase + MSC;
            while (idx < E && csr[idx] == cur) { prod *= x[ptrs[idx]]; ++idx; }
            out[cur] = prod;
            if (idx == E)
                for (int q = cur + 1; q < S; ++q) out[q] = 0.0f;
        } else {
            out[cur] = prod;
        }
    }
}

// Generic tail (E % MSC != 0) — R1-proven logic; not launched for E = 2^24.
#define TK 8
__global__ __launch_bounds__(256) void prodseg_tail(
    const float* __restrict__ x,
    const int*   __restrict__ ptrs,
    const int*   __restrict__ csr,
    float*       __restrict__ out,
    int E0, int E, int S)
{
    int t = blockIdx.x * blockDim.x + threadIdx.x;
    int base = E0 + t * TK;
    if (base >= E) return;
    int prev = (base == 0) ? -1 : csr[base - 1];
    int n = (base + TK <= E) ? TK : (E - base);

    int cur = 0; bool own = false; float prod = 1.0f;
    for (int k = 0; k < n; ++k) {
        int sg = csr[base + k];
        float gv = x[ptrs[base + k]];
        if (k == 0) {
            cur = sg; own = (sg != prev);
            prod = own ? gv : 1.0f;
            if (own) for (int q = prev + 1; q < cur; ++q) out[q] = 0.0f;
        } else if (sg == cur) {
            prod *= gv;
        } else {
            if (own) out[cur] = prod;
            for (int q = cur + 1; q < sg; ++q) out[q] = 0.0f;
            cur = sg; own = true; prod = gv;
        }
    }
    if (own) {
        int idx = base + n;
        while (idx < E && csr[idx] == cur) { prod *= x[ptrs[idx]]; ++idx; }
        out[cur] = prod;
        if (idx == E) for (int q = cur + 1; q < S; ++q) out[q] = 0.0f;
    }
}

extern "C" void kernel_launch(void* const* d_in, const int* in_sizes, int n_in,
                              void* d_out, int out_size, void* d_ws, size_t ws_size,
                              hipStream_t stream) {
    const float* x    = (const float*)d_in[0];
    const int*   ptrs = (const int*)d_in[1];
    const int*   csr  = (const int*)d_in[2];
    float*       out  = (float*)d_out;
    int N = in_sizes[0];
    int E = in_sizes[1];
    int S = out_size;

    // smallest shift with (N-1)>>shift < NWIN (17 for N=2^22 -> 512KB windows)
    int wshift = 0;
    while (((unsigned)(N - 1) >> wshift) >= NWIN) ++wshift;

    int F  = E / MSC;                  // full blocks (2048 for E=2^24)
    int E0 = F * MSC;

    // Exactly-resident launches: each launch's 1024 blocks are all
    // co-resident (4/CU) and march the windows together; the inter-launch
    // dependency is a free grid barrier separating x-passes.
    for (int scbase = 0; scbase < F; scbase += NBLK) {
        int nb = F - scbase; if (nb > NBLK) nb = NBLK;
        prodseg_main<<<nb, BLK, 0, stream>>>(x, ptrs, csr, out, E, S,
                                             wshift, scbase, F);
    }
    if (E0 < E) {
        int nt = (E - E0 + TK - 1) / TK;
        prodseg_tail<<<(nt + 255) / 256, 256, 0, stream>>>(x, ptrs, csr, out, E0, E, S);
    }
}